// Round 5
// baseline (35.179 us; speedup 1.0000x reference)
//
#include <hip/hip_runtime.h>

// out[b,l,t] = #points with ceil(dist(pcd[b,i], locs[l])) <= t+1, t=0..14
// For non-integer d: ceil(d) <= t+1  <=>  trunc(d) <= t.
// Per point: f = min(trunc(sqrt(d2)), 15); histogram h[f]; cnt[t] = prefix(h)[t].
// Bucket 15 is a garbage sink (never read).
//
// R5 structure:
//   1) transpose_kernel: AoS pcd (4,8192,3) -> SoA X/Y/Z in d_ws (393 KB).
//   2) feature_soa_kernel: wave-per-loc mapping; lane el reads float4 at
//      [k*64+lane] -> one 1KB segment per wave-load (16x fewer segments than
//      the 4-lane-broadcast mapping); loc is wave-uniform (readfirstlane ->
//      scalar loads); distance math in packed float2 -> v_pk_add/fma_f32.
// Histogram packed: u64 of 16x4-bit fields, dual accumulators, folded into
// 4x u32 byte-field accumulators (capacity 128 pts/thread <= 255).

#define BATCH 4
#define NPTS 8192
#define NLOC 2048
#define NT 15

typedef float v2f __attribute__((ext_vector_type(2)));

#if __has_builtin(__builtin_amdgcn_sqrtf)
#define FAST_SQRT(x) __builtin_amdgcn_sqrtf(x)
#else
#define FAST_SQRT(x) sqrtf(x)
#endif

// ---- 1) AoS (B*N,3) -> SoA X,Y,Z -------------------------------------------
__global__ __launch_bounds__(256) void transpose_kernel(
    const float* __restrict__ pcd, float* __restrict__ X,
    float* __restrict__ Y, float* __restrict__ Z)
{
    const int g = blockIdx.x * 256 + threadIdx.x;  // group of 4 points
    const float4* p = reinterpret_cast<const float4*>(pcd) + (size_t)g * 3;
    const float4 f0 = p[0], f1 = p[1], f2 = p[2];
    reinterpret_cast<float4*>(X)[g] = make_float4(f0.x, f0.w, f1.z, f2.y);
    reinterpret_cast<float4*>(Y)[g] = make_float4(f0.y, f1.x, f1.w, f2.z);
    reinterpret_cast<float4*>(Z)[g] = make_float4(f0.z, f1.y, f2.x, f2.w);
}

// ---- 2) main kernel: wave-per-loc, packed-f32 distance ---------------------
__global__ __launch_bounds__(256, 8) void feature_soa_kernel(
    const float* __restrict__ X, const float* __restrict__ Y,
    const float* __restrict__ Z, const float* __restrict__ locs,
    float* __restrict__ out)
{
    const int tid   = threadIdx.x;
    const int lane  = tid & 63;
    const int wv    = tid >> 6;              // 0..3 (wave id = loc within tile)
    const int b     = blockIdx.x >> 9;       // 0..3
    const int ltile = blockIdx.x & 511;      // 0..511
    // wave-uniform loc -> scalar loads for the loc coords
    const int loc   = __builtin_amdgcn_readfirstlane(ltile * 4 + wv);

    const float lx = locs[loc * 3 + 0];
    const float ly = locs[loc * 3 + 1];
    const float lz = locs[loc * 3 + 2];
    const v2f nlx = {-lx, -lx};
    const v2f nly = {-ly, -ly};
    const v2f nlz = {-lz, -lz};

    const float4* Xb = reinterpret_cast<const float4*>(X + (size_t)b * NPTS);
    const float4* Yb = reinterpret_cast<const float4*>(Y + (size_t)b * NPTS);
    const float4* Zb = reinterpret_cast<const float4*>(Z + (size_t)b * NPTS);

    // byte-field histogram accumulators:
    // h2[0]: buckets 0,2,4,6  h2[1]: 1,3,5,7  h2[2]: 8,10,12,14  h2[3]: 9,11,13,15
    unsigned int h2[4] = {0u, 0u, 0u, 0u};

    for (int bt = 0; bt < 16; ++bt) {        // 8 points per iteration
        const int i0 = (bt * 2 + 0) * 64 + lane;   // 1KB coalesced wave-load
        const int i1 = (bt * 2 + 1) * 64 + lane;
        const float4 xa = Xb[i0], ya = Yb[i0], za = Zb[i0];
        const float4 xc = Xb[i1], yc = Yb[i1], zc = Zb[i1];

        unsigned long long acc0 = 0ull, acc1 = 0ull;
#define DO_PAIR(A, X01, Y01, Z01)                                   \
        {                                                           \
            const v2f dx = (X01) + nlx;                             \
            const v2f dy = (Y01) + nly;                             \
            const v2f dz = (Z01) + nlz;                             \
            const v2f d2 = dx * dx + dy * dy + dz * dz;             \
            unsigned int fa = (unsigned int)FAST_SQRT(d2.x);        \
            unsigned int fb = (unsigned int)FAST_SQRT(d2.y);        \
            fa = fa < 15u ? fa : 15u;                               \
            fb = fb < 15u ? fb : 15u;                               \
            A += 1ull << (fa << 2);                                 \
            A += 1ull << (fb << 2);                                 \
        }
        {
            const v2f x01 = {xa.x, xa.y}, y01 = {ya.x, ya.y}, z01 = {za.x, za.y};
            const v2f x23 = {xa.z, xa.w}, y23 = {ya.z, ya.w}, z23 = {za.z, za.w};
            DO_PAIR(acc0, x01, y01, z01)
            DO_PAIR(acc1, x23, y23, z23)
        }
        {
            const v2f x01 = {xc.x, xc.y}, y01 = {yc.x, yc.y}, z01 = {zc.x, zc.y};
            const v2f x23 = {xc.z, xc.w}, y23 = {yc.z, yc.w}, z23 = {zc.z, zc.w};
            DO_PAIR(acc0, x01, y01, z01)
            DO_PAIR(acc1, x23, y23, z23)
        }
#undef DO_PAIR
        // nibbles: acc0,acc1 <= 4 each; sum <= 8 -> no nibble overflow
        const unsigned long long acc = acc0 + acc1;
        const unsigned int lo = (unsigned int)acc;
        const unsigned int hi = (unsigned int)(acc >> 32);
        h2[0] += lo & 0x0F0F0F0Fu;
        h2[1] += (lo >> 4) & 0x0F0F0F0Fu;
        h2[2] += hi & 0x0F0F0F0Fu;
        h2[3] += (hi >> 4) & 0x0F0F0F0Fu;
    }

    // Unpack 16 byte counters -> prefix sums; part[tid][t] = #(f <= t).
    unsigned int h[16];
#pragma unroll
    for (int j = 0; j < 16; ++j) {
        const unsigned int word = h2[(j & 1) + ((j >> 3) << 1)];
        h[j] = (word >> (8 * ((j >> 1) & 3))) & 0xFFu;
    }

    __shared__ int part[256][17];  // odd stride: conflict-free writes
    unsigned int p = 0;
#pragma unroll
    for (int t = 0; t < NT; ++t) { p += h[t]; part[tid][t] = (int)p; }
    __syncthreads();

    // Reduce the 64 lanes per loc; one writer per output element.
    if (tid < 4 * NT) {
        const int li2 = tid / NT;       // 0..3 (wave/loc within tile)
        const int t   = tid - li2 * NT; // 0..14
        int s = 0;
#pragma unroll
        for (int k = 0; k < 64; ++k)
            s += part[li2 * 64 + k][t];
        out[((size_t)b * NLOC + (size_t)(ltile * 4 + li2)) * NT + t] = (float)s;
    }
}

// ---- fallback (R4 kernel) if ws_size is too small --------------------------
#define SPLITS 64
#define LOCS_PER_BLOCK 4
#define PPS (NPTS / SPLITS)

__global__ __launch_bounds__(256) void manual_feature_fallback(
    const float* __restrict__ pcd, const float* __restrict__ locs,
    float* __restrict__ out)
{
    const int tid   = threadIdx.x;
    const int li    = tid & (LOCS_PER_BLOCK - 1);
    const int split = tid >> 2;
    const int b     = blockIdx.x >> 9;
    const int ltile = blockIdx.x & 511;
    const int loc   = ltile * LOCS_PER_BLOCK + li;

    const float lx = locs[loc * 3 + 0];
    const float ly = locs[loc * 3 + 1];
    const float lz = locs[loc * 3 + 2];

    unsigned int h2[4] = {0u, 0u, 0u, 0u};
    const float4* base =
        reinterpret_cast<const float4*>(pcd + (size_t)(b * NPTS + split * PPS) * 3);

#pragma unroll 4
    for (int bt = 0; bt < PPS / 8; ++bt) {
        const float4 f0 = base[bt * 6 + 0];
        const float4 f1 = base[bt * 6 + 1];
        const float4 f2 = base[bt * 6 + 2];
        const float4 f3 = base[bt * 6 + 3];
        const float4 f4 = base[bt * 6 + 4];
        const float4 f5 = base[bt * 6 + 5];

        unsigned long long acc0 = 0ull, acc1 = 0ull;
        {
            float dx, dy, dz, d2, d;
            unsigned int f;
#define DO_POINT(A, PX, PY, PZ)                                     \
            dx = (PX) - lx; dy = (PY) - ly; dz = (PZ) - lz;         \
            d2 = dx * dx + dy * dy + dz * dz;                       \
            d  = FAST_SQRT(d2);                                     \
            f  = (unsigned int)d;                                   \
            f  = (f < 15u) ? f : 15u;                               \
            A += 1ull << (4u * f);

            DO_POINT(acc0, f0.x, f0.y, f0.z)
            DO_POINT(acc1, f0.w, f1.x, f1.y)
            DO_POINT(acc0, f1.z, f1.w, f2.x)
            DO_POINT(acc1, f2.y, f2.z, f2.w)
            DO_POINT(acc0, f3.x, f3.y, f3.z)
            DO_POINT(acc1, f3.w, f4.x, f4.y)
            DO_POINT(acc0, f4.z, f4.w, f5.x)
            DO_POINT(acc1, f5.y, f5.z, f5.w)
#undef DO_POINT
        }
        const unsigned long long acc = acc0 + acc1;
        const unsigned int lo = (unsigned int)acc;
        const unsigned int hi = (unsigned int)(acc >> 32);
        h2[0] += lo & 0x0F0F0F0Fu;
        h2[1] += (lo >> 4) & 0x0F0F0F0Fu;
        h2[2] += hi & 0x0F0F0F0Fu;
        h2[3] += (hi >> 4) & 0x0F0F0F0Fu;
    }

    unsigned int h[16];
#pragma unroll
    for (int j = 0; j < 16; ++j) {
        const unsigned int word = h2[(j & 1) + ((j >> 3) << 1)];
        h[j] = (word >> (8 * ((j >> 1) & 3))) & 0xFFu;
    }

    __shared__ int part[256][17];
    unsigned int p = 0;
#pragma unroll
    for (int t = 0; t < NT; ++t) { p += h[t]; part[tid][t] = (int)p; }
    __syncthreads();

    if (tid < LOCS_PER_BLOCK * NT) {
        const int li2 = tid / NT;
        const int t   = tid - li2 * NT;
        int s = 0;
#pragma unroll
        for (int k = 0; k < SPLITS; ++k)
            s += part[k * LOCS_PER_BLOCK + li2][t];
        out[((size_t)b * NLOC + (size_t)(ltile * LOCS_PER_BLOCK + li2)) * NT + t] =
            (float)s;
    }
}

extern "C" void kernel_launch(void* const* d_in, const int* in_sizes, int n_in,
                              void* d_out, int out_size, void* d_ws, size_t ws_size,
                              hipStream_t stream) {
    const float* pcd  = (const float*)d_in[0];
    const float* locs = (const float*)d_in[1];
    float* out = (float*)d_out;

    const size_t need = (size_t)BATCH * NPTS * 3 * sizeof(float);  // 393,216 B
    if (ws_size >= need) {
        float* X = (float*)d_ws;
        float* Y = X + (size_t)BATCH * NPTS;
        float* Z = Y + (size_t)BATCH * NPTS;
        transpose_kernel<<<dim3(BATCH * NPTS / 4 / 256), dim3(256), 0, stream>>>(
            pcd, X, Y, Z);
        feature_soa_kernel<<<dim3(BATCH * (NLOC / 4)), dim3(256), 0, stream>>>(
            X, Y, Z, locs, out);
    } else {
        manual_feature_fallback<<<dim3(BATCH * (NLOC / 4)), dim3(256), 0,
                                  stream>>>(pcd, locs, out);
    }
}

// Round 6
// 25.817 us; speedup vs baseline: 1.3626x; 1.3626x over previous
//
#include <hip/hip_runtime.h>

// out[b,l,t] = #points with ceil(dist(pcd[b,i], locs[l])) <= t+1, t=0..14
// ceil(d)<=t+1 (d non-integer) <=> trunc(d)<=t: f=min(trunc(sqrt(d2)),15),
// histogram h[f], cnt[t]=prefix(h)[t]. Bucket 15 = garbage sink (never read).
//
// R6 mapping: locs grid is (16,16,8) z-fastest -> any aligned 4-loc group
// shares (x,y). Block = 4 consecutive locs x all 8192 points; thread =
// one point per iter vs all 4 locs => dx^2+dy^2 computed ONCE per 4 pairs.
// Wave loads 64 consecutive float3s = 768B contiguous (dense segments).
// Per-thread: 4 packed nibble-acc u64 (fold every 8 pts) -> 4x4 u32 byte
// counters (<=32/thread); bucket-15 masked off at fold (sink can overflow).
// Epilogue: staged LDS reduce bytes->u16x2->u32, then prefix, 1 writer/out.

#define BATCH 4
#define NPTS 8192
#define NLOC 2048
#define NT 15

#if __has_builtin(__builtin_amdgcn_sqrtf)
#define FAST_SQRT(x) __builtin_amdgcn_sqrtf(x)
#else
#define FAST_SQRT(x) sqrtf(x)
#endif

struct f3 { float x, y, z; };

__global__ __launch_bounds__(256) void manual_feature_kernel(
    const float* __restrict__ pcd, const float* __restrict__ locs,
    float* __restrict__ out)
{
    const int tid  = threadIdx.x;
    const int b    = blockIdx.x >> 9;     // 0..3
    const int lt   = blockIdx.x & 511;    // 0..511
    const int loc0 = lt * 4;              // 4 consecutive locs: same (x,y), z-col

    const float lx = locs[loc0 * 3 + 0];
    const float ly = locs[loc0 * 3 + 1];
    float lz[4];
#pragma unroll
    for (int j = 0; j < 4; ++j) lz[j] = locs[(loc0 + j) * 3 + 2];

    // h2[loc][w]: byte-packed counts. w0: buckets 0,2,4,6  w1: 1,3,5,7
    // w2: 8,10,12,14  w3: 9,11,13,(15 dropped)
    uint h2[4][4];
#pragma unroll
    for (int j = 0; j < 4; ++j)
#pragma unroll
        for (int w = 0; w < 4; ++w) h2[j][w] = 0u;

    const f3* P = reinterpret_cast<const f3*>(pcd + (size_t)b * NPTS * 3);

    for (int k8 = 0; k8 < 4; ++k8) {      // 4 fold periods x 8 points
        unsigned long long acc[4] = {0ull, 0ull, 0ull, 0ull};
#pragma unroll
        for (int kk = 0; kk < 8; ++kk) {
            const int p = (k8 * 8 + kk) * 256 + tid;
            const f3 pt = P[p];
            const float dx = pt.x - lx;
            const float dy = pt.y - ly;
            const float dxy2 = dx * dx + dy * dy;
#pragma unroll
            for (int j = 0; j < 4; ++j) {
                const float dz = pt.z - lz[j];
                const float d2 = dz * dz + dxy2;   // fma
                const float d  = FAST_SQRT(d2);
                uint f = (uint)d;                  // trunc
                f = f < 15u ? f : 15u;             // clamp into sink
                acc[j] += 1ull << (f << 2);        // nibble add, <=8 per period
            }
        }
#pragma unroll
        for (int j = 0; j < 4; ++j) {
            const uint lo = (uint)acc[j];
            const uint hi = (uint)(acc[j] >> 32);
            h2[j][0] += lo & 0x0F0F0F0Fu;
            h2[j][1] += (lo >> 4) & 0x0F0F0F0Fu;
            h2[j][2] += hi & 0x0F0F0F0Fu;
            h2[j][3] += (hi >> 4) & 0x000F0F0Fu;   // drop bucket-15 sink
        }
    }

    // ---- staged reduction over the 256 threads -----------------------------
    __shared__ uint smem1[256][17];   // [thread][loc*4+w], odd stride
#pragma unroll
    for (int j = 0; j < 4; ++j)
#pragma unroll
        for (int w = 0; w < 4; ++w) smem1[tid][j * 4 + w] = h2[j][w];
    __syncthreads();

    // Stage 2: (loc,w,chunk) sums 16 threads, bytes split into u16 pairs.
    // capacity: 16 threads x <=32 = 512 < 65536.
    __shared__ uint s2lo[4][4][16];   // bytes 0(lo16),2(hi16)
    __shared__ uint s2hi[4][4][16];   // bytes 1(lo16),3(hi16)
    {
        const int loc = tid >> 6, w = (tid >> 4) & 3, ch = tid & 15;
        uint alo = 0u, ahi = 0u;
#pragma unroll
        for (int it = 0; it < 16; ++it) {
            const uint v = smem1[ch * 16 + it][loc * 4 + w];
            alo += v & 0x00FF00FFu;
            ahi += (v >> 8) & 0x00FF00FFu;
        }
        s2lo[loc][w][ch] = alo;
        s2hi[loc][w][ch] = ahi;
    }
    __syncthreads();

    // Stage 3a: (loc,bucket) sums the 16 chunks -> full u32 count.
    __shared__ uint hfull[4][16];
    if (tid < 64) {
        const int loc = tid >> 4, bkt = tid & 15;
        const int w  = (bkt & 1) + ((bkt >> 3) << 1);
        const int by = (bkt >> 1) & 3;
        const uint* src = (by & 1) ? &s2hi[loc][w][0] : &s2lo[loc][w][0];
        const int sh = (by >> 1) * 16;
        uint s = 0u;
#pragma unroll
        for (int ch = 0; ch < 16; ++ch) s += (src[ch] >> sh) & 0xFFFFu;
        hfull[loc][bkt] = s;
    }
    __syncthreads();

    // Stage 3b: prefix over buckets; one writer per output element.
    if (tid < 60) {
        const int loc = tid / 15, t = tid - loc * 15;
        uint s = 0u;
#pragma unroll
        for (int bkt = 0; bkt < NT; ++bkt) s += (bkt <= t) ? hfull[loc][bkt] : 0u;
        out[((size_t)b * NLOC + (size_t)(loc0 + loc)) * NT + t] = (float)s;
    }
}

extern "C" void kernel_launch(void* const* d_in, const int* in_sizes, int n_in,
                              void* d_out, int out_size, void* d_ws, size_t ws_size,
                              hipStream_t stream) {
    const float* pcd  = (const float*)d_in[0];
    const float* locs = (const float*)d_in[1];
    float* out = (float*)d_out;
    manual_feature_kernel<<<dim3(BATCH * (NLOC / 4)), dim3(256), 0, stream>>>(
        pcd, locs, out);
}